// Round 3
// baseline (373.776 us; speedup 1.0000x reference)
//
#include <hip/hip_runtime.h>
#include <math.h>

// Problem constants
#define LQ    512
#define DS    384
#define DPAIR 128
#define NH    12
#define NPP   1792   // padded projection width
#define TJC   64     // j-chunk for pair kernel
#define NC    8      // number of j-chunks (LQ/TJC)

typedef unsigned short u16;
typedef unsigned int   u32;
typedef __attribute__((ext_vector_type(8))) short bf16x8;  // 8 bf16 in 4 VGPRs
typedef __attribute__((ext_vector_type(4))) float f32x4;

// round-to-nearest-even f32 -> bf16 bits
__device__ inline u16 bf16_rne(float x) {
  u32 u = __float_as_uint(x);
  u32 r = (u + 0x7FFFu + ((u >> 16) & 1u)) >> 16;
  return (u16)r;
}
// split x ~= hi + lo (both bf16); residual ~2^-17 relative
__device__ inline void split_bf16(float x, u16& h, u16& l) {
  u16 hb = bf16_rne(x);
  float hf = __uint_as_float(((u32)hb) << 16);
  h = hb;
  l = bf16_rne(x - hf);
}

// ---------------------------------------------------------------- fused prep:
// blocks 0..167   : Wcat transpose+split tiles -> WcatT [NPP][DS] bf16 hi/lo
// block  168      : bcat + WpbT
// blocks 169..384 : Wo transpose+split tiles   -> WoT [384][2304] bf16 hi/lo
// blocks 385..896 : layernorm rows -> sn split-bf16
__global__ __launch_bounds__(256) void k_prep(
    const float* __restrict__ Wq, const float* __restrict__ Wk,
    const float* __restrict__ Wv, const float* __restrict__ Wqp,
    const float* __restrict__ Wkp, const float* __restrict__ Wvp,
    const float* __restrict__ bq, const float* __restrict__ bk,
    const float* __restrict__ bv, const float* __restrict__ bqp,
    const float* __restrict__ bkp, const float* __restrict__ bvp,
    const float* __restrict__ Wpb, const float* __restrict__ Wo,
    const float* __restrict__ xs, const float* __restrict__ ln_w,
    const float* __restrict__ ln_b,
    u16* __restrict__ Wth, u16* __restrict__ Wtl,
    float* __restrict__ bcat, float* __restrict__ WpbT,
    u16* __restrict__ WoTh, u16* __restrict__ WoTl,
    u16* __restrict__ snh, u16* __restrict__ snl) {
  __shared__ u16 sh_hi[64][66], sh_lo[64][66];   // stride 66 -> conflict-free
  int blk = blockIdx.x, t = threadIdx.x;
  if (blk < 168) {
    int kb = blk / 28, cb = blk % 28;
    int k0 = kb * 64, c0 = cb * 64;
    for (int e = t; e < 4096; e += 256) {
      int rr = e >> 6, cc = e & 63;
      int k = k0 + rr, c = c0 + cc;
      float v = 0.f;
      if (c < 384)       v = Wq[k*384 + c];
      else if (c < 768)  v = Wk[k*384 + c-384];
      else if (c < 1152) v = Wv[k*384 + c-768];
      else if (c < 1296) v = Wqp[k*144 + c-1152];
      else if (c < 1440) v = Wkp[k*144 + c-1296];
      else if (c < 1728) v = Wvp[k*288 + c-1440];
      u16 h_, l_; split_bf16(v, h_, l_);
      sh_hi[rr][cc] = h_; sh_lo[rr][cc] = l_;
    }
    __syncthreads();
    for (int e = t; e < 4096; e += 256) {
      int cc = e >> 6, kk = e & 63;
      Wth[(size_t)(c0+cc)*DS + k0 + kk] = sh_hi[kk][cc];
      Wtl[(size_t)(c0+cc)*DS + k0 + kk] = sh_lo[kk][cc];
    }
  } else if (blk == 168) {
    for (int e = t; e < NPP + NH*DPAIR; e += 256) {
      if (e < NPP) {
        int c = e;
        float v = 0.f;
        if (c < 384)       v = bq[c];
        else if (c < 768)  v = bk[c-384];
        else if (c < 1152) v = bv[c-768];
        else if (c < 1296) v = bqp[c-1152];
        else if (c < 1440) v = bkp[c-1296];
        else if (c < 1728) v = bvp[c-1440];
        bcat[c] = v;
      } else {
        int e2 = e - NPP;
        int k = e2 / NH, h = e2 % NH;
        WpbT[h*DPAIR + k] = Wpb[e2];
      }
    }
  } else if (blk < 385) {
    int idx = blk - 169;
    int kt = idx % 36, nt = idx / 36;      // Wo is [2304][384]
    int k0 = kt * 64, n0 = nt * 64;
    for (int e = t; e < 4096; e += 256) {
      int rr = e >> 6, cc = e & 63;
      float v = Wo[(size_t)(k0+rr)*384 + n0 + cc];
      u16 h_, l_; split_bf16(v, h_, l_);
      sh_hi[rr][cc] = h_; sh_lo[rr][cc] = l_;
    }
    __syncthreads();
    for (int e = t; e < 4096; e += 256) {
      int cc = e >> 6, kk = e & 63;
      WoTh[(size_t)(n0+cc)*2304 + k0 + kk] = sh_hi[kk][cc];
      WoTl[(size_t)(n0+cc)*2304 + k0 + kk] = sh_lo[kk][cc];
    }
  } else {
    // layernorm row, 256 threads covering 384 elements
    int i = blk - 385;
    float* red = (float*)&sh_hi[0][0];
    float a0 = xs[i*DS + t];
    float a1 = (t < 128) ? xs[i*DS + 256 + t] : 0.f;
    red[t] = a0 + a1; __syncthreads();
    for (int s = 128; s > 0; s >>= 1) { if (t < s) red[t] += red[t+s]; __syncthreads(); }
    float mu = red[0] * (1.f/384.f);
    __syncthreads();
    float d0 = a0 - mu, d1 = (t < 128) ? (a1 - mu) : 0.f;
    red[t] = d0*d0 + d1*d1; __syncthreads();
    for (int s = 128; s > 0; s >>= 1) { if (t < s) red[t] += red[t+s]; __syncthreads(); }
    float rstd = rsqrtf(red[0] * (1.f/384.f) + 1e-5f);
    u16 h_, l_;
    float y0 = d0*rstd*ln_w[t] + ln_b[t];
    split_bf16(y0, h_, l_); snh[i*DS + t] = h_; snl[i*DS + t] = l_;
    if (t < 128) {
      float y1 = d1*rstd*ln_w[256+t] + ln_b[256+t];
      split_bf16(y1, h_, l_); snh[i*DS + 256 + t] = h_; snl[i*DS + 256 + t] = l_;
    }
  }
}

// ---------------------------------------------------------------- MFMA GEMM: C[M][N] = A[M][K] @ Bt[N][K]^T
// 3-term compensated bf16 (AhBh + AhBl + AlBh), f32 accumulate -> ~f32 accuracy.
__global__ __launch_bounds__(256) void k_gemm_mfma(
    const u16* __restrict__ Ah, const u16* __restrict__ Al,
    const u16* __restrict__ Bth, const u16* __restrict__ Btl,
    const float* __restrict__ bias, float* __restrict__ C,
    float* __restrict__ Cpart, int M, int N, int K) {
  int t = threadIdx.x;
  int lane = t & 63, wave = t >> 6;
  int wr = wave >> 1, wc = wave & 1;
  int i0 = blockIdx.y * 64 + wr * 32;
  int j0 = blockIdx.x * 64 + wc * 32;
  int KS = gridDim.z;
  int kper = K / KS;
  size_t kbeg = (size_t)blockIdx.z * kper;
  int lr = lane & 15, lk = (lane >> 4) << 3;

  const u16* a0h = Ah  + (size_t)(i0 + lr) * K + kbeg + lk;
  const u16* a1h = a0h + (size_t)16 * K;
  const u16* a0l = Al  + (size_t)(i0 + lr) * K + kbeg + lk;
  const u16* a1l = a0l + (size_t)16 * K;
  const u16* b0h = Bth + (size_t)(j0 + lr) * K + kbeg + lk;
  const u16* b1h = b0h + (size_t)16 * K;
  const u16* b0l = Btl + (size_t)(j0 + lr) * K + kbeg + lk;
  const u16* b1l = b0l + (size_t)16 * K;

  f32x4 c00 = {0.f,0.f,0.f,0.f}, c01 = c00, c10 = c00, c11 = c00;
  for (int k = 0; k < kper; k += 32) {
    bf16x8 A0h = *(const bf16x8*)(a0h + k);
    bf16x8 A1h = *(const bf16x8*)(a1h + k);
    bf16x8 B0h = *(const bf16x8*)(b0h + k);
    bf16x8 B1h = *(const bf16x8*)(b1h + k);
    bf16x8 A0l = *(const bf16x8*)(a0l + k);
    bf16x8 A1l = *(const bf16x8*)(a1l + k);
    bf16x8 B0l = *(const bf16x8*)(b0l + k);
    bf16x8 B1l = *(const bf16x8*)(b1l + k);
    c00 = __builtin_amdgcn_mfma_f32_16x16x32_bf16(A0h, B0h, c00, 0, 0, 0);
    c01 = __builtin_amdgcn_mfma_f32_16x16x32_bf16(A0h, B1h, c01, 0, 0, 0);
    c10 = __builtin_amdgcn_mfma_f32_16x16x32_bf16(A1h, B0h, c10, 0, 0, 0);
    c11 = __builtin_amdgcn_mfma_f32_16x16x32_bf16(A1h, B1h, c11, 0, 0, 0);
    c00 = __builtin_amdgcn_mfma_f32_16x16x32_bf16(A0h, B0l, c00, 0, 0, 0);
    c01 = __builtin_amdgcn_mfma_f32_16x16x32_bf16(A0h, B1l, c01, 0, 0, 0);
    c10 = __builtin_amdgcn_mfma_f32_16x16x32_bf16(A1h, B0l, c10, 0, 0, 0);
    c11 = __builtin_amdgcn_mfma_f32_16x16x32_bf16(A1h, B1l, c11, 0, 0, 0);
    c00 = __builtin_amdgcn_mfma_f32_16x16x32_bf16(A0l, B0h, c00, 0, 0, 0);
    c01 = __builtin_amdgcn_mfma_f32_16x16x32_bf16(A0l, B1h, c01, 0, 0, 0);
    c10 = __builtin_amdgcn_mfma_f32_16x16x32_bf16(A1l, B0h, c10, 0, 0, 0);
    c11 = __builtin_amdgcn_mfma_f32_16x16x32_bf16(A1l, B1h, c11, 0, 0, 0);
  }

  int orow = (lane >> 4) << 2;
  int col0 = j0 + lr, col1 = j0 + 16 + lr;
  if (KS == 1) {
    float bb0 = bias[col0], bb1 = bias[col1];
    #pragma unroll
    for (int r = 0; r < 4; r++) {
      int row0 = i0 + orow + r, row1 = row0 + 16;
      C[(size_t)row0*N + col0] = c00[r] + bb0;
      C[(size_t)row0*N + col1] = c01[r] + bb1;
      C[(size_t)row1*N + col0] = c10[r] + bb0;
      C[(size_t)row1*N + col1] = c11[r] + bb1;
    }
  } else {
    float* dst = Cpart + (size_t)blockIdx.z * M * N;
    #pragma unroll
    for (int r = 0; r < 4; r++) {
      int row0 = i0 + orow + r, row1 = row0 + 16;
      dst[(size_t)row0*N + col0] = c00[r];
      dst[(size_t)row0*N + col1] = c01[r];
      dst[(size_t)row1*N + col0] = c10[r];
      dst[(size_t)row1*N + col1] = c11[r];
    }
  }
}

__global__ void k_reduce_bias(const float* __restrict__ part, const float* __restrict__ bias,
                              float* __restrict__ out, int MN, int N, int KS) {
  int e = blockIdx.x * 256 + threadIdx.x;
  if (e >= MN) return;
  float s = bias[e % N];
  for (int z = 0; z < KS; z++) s += part[(size_t)z*MN + e];
  out[e] = s;
}

// ---------------------------------------------------------------- fused feature-build + logits MFMA
// Per block (i-tile, j-tile, h): build 64 A-feature rows and 64 B-feature rows
// (48 dims + pad to 64) in LDS directly from C1/rot/trans, then 64x64 MFMA -> S.
__global__ __launch_bounds__(256) void k_feat_logits(
    const float* __restrict__ C1, const float* __restrict__ rot,
    const float* __restrict__ trans, const float* __restrict__ gamma,
    const float* __restrict__ w_c, const float* __restrict__ w_l,
    float* __restrict__ S) {
  __shared__ u16 Ash[64][72], Asl[64][72], Bsh[64][72], Bsl[64][72];  // 36.9 KB
  int h = blockIdx.z;
  int i0 = blockIdx.y * 64, j0 = blockIdx.x * 64;
  int t = threadIdx.x;

  if (t < 128) {
    int row = t & 63, side = t >> 6;      // side 0 = A (query), 1 = B (key)
    int gi = (side ? j0 : i0) + row;
    float R[9], tr[3];
    #pragma unroll
    for (int r = 0; r < 9; r++) R[r] = rot[(size_t)gi*9 + r];
    #pragma unroll
    for (int r = 0; r < 3; r++) tr[r] = trans[(size_t)gi*3 + r];
    float sc = w_c[0] * rsqrtf(32.f);
    float gp = gamma[h] * w_l[0];
    u16 (*Fh)[72] = side ? Bsh : Ash;
    u16 (*Fl)[72] = side ? Bsl : Asl;
    const float* qk = C1 + (size_t)gi*NPP + (side ? 384 : 0) + h*32;
    u16 h_, l_;
    #pragma unroll 8
    for (int d = 0; d < 32; d++) {
      float v = side ? qk[d] : sc*qk[d];
      split_bf16(v, h_, l_); Fh[row][d] = h_; Fl[row][d] = l_;
    }
    const float* pp = C1 + (size_t)gi*NPP + (side ? 1296 : 1152) + h*12;
    float ss = 0.f;
    #pragma unroll
    for (int p = 0; p < 4; p++) {
      float x = pp[p*3], y = pp[p*3+1], z = pp[p*3+2];
      #pragma unroll
      for (int r = 0; r < 3; r++) {
        float g = fmaf(R[r*3],x, fmaf(R[r*3+1],y, fmaf(R[r*3+2],z, tr[r])));
        float v = side ? g : gp*g;
        split_bf16(v, h_, l_); Fh[row][32+p*3+r] = h_; Fl[row][32+p*3+r] = l_;
        ss = fmaf(g,g,ss);
      }
    }
    float c44 = side ? 1.f : -0.5f*gp*ss;
    float c45 = side ? -0.5f*gp*ss : 1.f;
    split_bf16(c44, h_, l_); Fh[row][44] = h_; Fl[row][44] = l_;
    split_bf16(c45, h_, l_); Fh[row][45] = h_; Fl[row][45] = l_;
    #pragma unroll
    for (int d = 46; d < 64; d++) { Fh[row][d] = 0; Fl[row][d] = 0; }
  }
  __syncthreads();

  int lane = t & 63, wave = t >> 6, wr = wave >> 1, wc = wave & 1;
  int lr = lane & 15, lk = (lane >> 4) << 3;
  f32x4 c00 = {0.f,0.f,0.f,0.f}, c01 = c00, c10 = c00, c11 = c00;
  #pragma unroll
  for (int ks = 0; ks < 64; ks += 32) {
    bf16x8 A0h = *(const bf16x8*)&Ash[wr*32 + lr][ks + lk];
    bf16x8 A1h = *(const bf16x8*)&Ash[wr*32 + 16 + lr][ks + lk];
    bf16x8 B0h = *(const bf16x8*)&Bsh[wc*32 + lr][ks + lk];
    bf16x8 B1h = *(const bf16x8*)&Bsh[wc*32 + 16 + lr][ks + lk];
    bf16x8 A0l = *(const bf16x8*)&Asl[wr*32 + lr][ks + lk];
    bf16x8 A1l = *(const bf16x8*)&Asl[wr*32 + 16 + lr][ks + lk];
    bf16x8 B0l = *(const bf16x8*)&Bsl[wc*32 + lr][ks + lk];
    bf16x8 B1l = *(const bf16x8*)&Bsl[wc*32 + 16 + lr][ks + lk];
    c00 = __builtin_amdgcn_mfma_f32_16x16x32_bf16(A0h, B0h, c00, 0, 0, 0);
    c01 = __builtin_amdgcn_mfma_f32_16x16x32_bf16(A0h, B1h, c01, 0, 0, 0);
    c10 = __builtin_amdgcn_mfma_f32_16x16x32_bf16(A1h, B0h, c10, 0, 0, 0);
    c11 = __builtin_amdgcn_mfma_f32_16x16x32_bf16(A1h, B1h, c11, 0, 0, 0);
    c00 = __builtin_amdgcn_mfma_f32_16x16x32_bf16(A0h, B0l, c00, 0, 0, 0);
    c01 = __builtin_amdgcn_mfma_f32_16x16x32_bf16(A0h, B1l, c01, 0, 0, 0);
    c10 = __builtin_amdgcn_mfma_f32_16x16x32_bf16(A1h, B0l, c10, 0, 0, 0);
    c11 = __builtin_amdgcn_mfma_f32_16x16x32_bf16(A1h, B1l, c11, 0, 0, 0);
    c00 = __builtin_amdgcn_mfma_f32_16x16x32_bf16(A0l, B0h, c00, 0, 0, 0);
    c01 = __builtin_amdgcn_mfma_f32_16x16x32_bf16(A0l, B1h, c01, 0, 0, 0);
    c10 = __builtin_amdgcn_mfma_f32_16x16x32_bf16(A1l, B0h, c10, 0, 0, 0);
    c11 = __builtin_amdgcn_mfma_f32_16x16x32_bf16(A1l, B1h, c11, 0, 0, 0);
  }

  int orow = (lane >> 4) << 2;
  int col0 = j0 + wc*32 + lr, col1 = col0 + 16;
  int rbase = i0 + wr*32 + orow;
  #pragma unroll
  for (int r = 0; r < 4; r++) {
    S[((size_t)h*LQ + rbase + r)*LQ + col0]      = c00[r];
    S[((size_t)h*LQ + rbase + r)*LQ + col1]      = c01[r];
    S[((size_t)h*LQ + rbase + 16 + r)*LQ + col0] = c10[r];
    S[((size_t)h*LQ + rbase + 16 + r)*LQ + col1] = c11[r];
  }
}

// ---------------------------------------------------------------- pair chunk: bias + chunk softmax + partial pair_out
__global__ __launch_bounds__(256, 2) void k_pair_chunk(
    const float* __restrict__ pair, const float* __restrict__ WpbT,
    const float* __restrict__ bpb, const float* __restrict__ mask,
    float* __restrict__ S, float* __restrict__ pairpart, float* __restrict__ msum) {
  __shared__ float tile[TJC*133];
  __shared__ float wt[NH*TJC];
  int i = blockIdx.x, c = blockIdx.y, t = threadIdx.x;
  int j0 = c*TJC;

  const float4* src = (const float4*)(pair + ((size_t)i*LQ + j0)*DPAIR);
  #pragma unroll
  for (int u = 0; u < 8; u++) {
    int e = t + u*256; int row = e >> 5, c4 = e & 31;
    *(float4*)&tile[row*133 + c4*4] = src[e];
  }

  int j = t & 63;
  int hg = __builtin_amdgcn_readfirstlane(t >> 6);
  int h0 = hg*3;
  float l[3];
  #pragma unroll
  for (int q = 0; q < 3; q++)
    l[q] = S[((size_t)(h0+q)*LQ + i)*LQ + j0 + j] + bpb[h0+q];
  bool dead = (mask[i] * mask[j0 + j] <= 0.f);
  __syncthreads();

  {
    const float* w0p = WpbT + (size_t)(h0+0)*DPAIR;
    const float* w1p = WpbT + (size_t)(h0+1)*DPAIR;
    const float* w2p = WpbT + (size_t)(h0+2)*DPAIR;
    float a0 = 0.f, a1 = 0.f, a2 = 0.f;
    #pragma unroll 8
    for (int k = 0; k < DPAIR; k += 4) {
      float4 pv = *(const float4*)&tile[j*133 + k];
      float4 w0 = *(const float4*)(w0p + k);
      float4 w1 = *(const float4*)(w1p + k);
      float4 w2 = *(const float4*)(w2p + k);
      a0 = fmaf(pv.x,w0.x, fmaf(pv.y,w0.y, fmaf(pv.z,w0.z, fmaf(pv.w,w0.w, a0))));
      a1 = fmaf(pv.x,w1.x, fmaf(pv.y,w1.y, fmaf(pv.z,w1.z, fmaf(pv.w,w1.w, a1))));
      a2 = fmaf(pv.x,w2.x, fmaf(pv.y,w2.y, fmaf(pv.z,w2.z, fmaf(pv.w,w2.w, a2))));
    }
    l[0] += a0; l[1] += a1; l[2] += a2;
    if (dead) { l[0] = -1e9f; l[1] = -1e9f; l[2] = -1e9f; }
  }

  #pragma unroll
  for (int q = 0; q < 3; q++) {
    float m = l[q];
    #pragma unroll
    for (int o = 32; o > 0; o >>= 1) m = fmaxf(m, __shfl_xor(m, o, 64));
    float w = __expf(l[q] - m);
    float sm = w;
    #pragma unroll
    for (int o = 32; o > 0; o >>= 1) sm += __shfl_xor(sm, o, 64);
    wt[(h0+q)*TJC + j] = w;
    S[((size_t)(h0+q)*LQ + i)*LQ + j0 + j] = w;
    if (j == 0) {
      float* dst = msum + (((size_t)i*NC + c)*NH + h0 + q)*2;
      dst[0] = m; dst[1] = sm;
    }
  }
  __syncthreads();

  int dg = t & 31, strip = t >> 5, jb = strip*8;
  float4 pv[8];
  #pragma unroll
  for (int q = 0; q < 8; q++) pv[q] = *(const float4*)&tile[(jb+q)*133 + dg*4];
  float4 acc[NH];
  #pragma unroll
  for (int h = 0; h < NH; h++) acc[h] = make_float4(0.f,0.f,0.f,0.f);
  #pragma unroll
  for (int h = 0; h < NH; h++) {
    float4 w0 = *(const float4*)&wt[h*TJC + jb];
    float4 w1 = *(const float4*)&wt[h*TJC + jb + 4];
    float wq[8] = {w0.x,w0.y,w0.z,w0.w,w1.x,w1.y,w1.z,w1.w};
    float4 a = acc[h];
    #pragma unroll
    for (int q = 0; q < 8; q++) {
      a.x = fmaf(wq[q], pv[q].x, a.x);
      a.y = fmaf(wq[q], pv[q].y, a.y);
      a.z = fmaf(wq[q], pv[q].z, a.z);
      a.w = fmaf(wq[q], pv[q].w, a.w);
    }
    acc[h] = a;
  }
  __syncthreads();

  float4* red4 = (float4*)tile;
  float4 tot[2];
  tot[0] = make_float4(0.f,0.f,0.f,0.f);
  tot[1] = make_float4(0.f,0.f,0.f,0.f);
  #pragma unroll
  for (int half = 0; half < 2; half++) {
    if ((strip >> 2) == half) {
      #pragma unroll
      for (int h = 0; h < NH; h++)
        red4[(((strip & 3)*NH) + h)*32 + dg] = acc[h];
    }
    __syncthreads();
    for (int e = t, u = 0; e < NH*32; e += 256, u++) {
      int rh = e >> 5, rd = e & 31;
      #pragma unroll
      for (int s4 = 0; s4 < 4; s4++) {
        float4 v = red4[((s4*NH) + rh)*32 + rd];
        tot[u].x += v.x; tot[u].y += v.y; tot[u].z += v.z; tot[u].w += v.w;
      }
    }
    __syncthreads();
  }
  for (int e = t, u = 0; e < NH*32; e += 256, u++) {
    int rh = e >> 5, rd = e & 31;
    *(float4*)&pairpart[(((size_t)i*NC + c)*NH + rh)*DPAIR + rd*4] = tot[u];
  }
}

// ---------------------------------------------------------------- fused attention tail:
// per block (64-row i-tile, head h): scs from msum; pairpart->comb combine;
// K-loop j-chunks: stage normalized weights (split-bf16) + build V/vg operand
// transposed in LDS from C1/rot; full-K compensated MFMA; avpts epilogue.
__global__ __launch_bounds__(256, 2) void k_attn_full(
    const float* __restrict__ S, const float* __restrict__ msum,
    const float* __restrict__ pairpart,
    const float* __restrict__ C1, const float* __restrict__ rot,
    const float* __restrict__ trans,
    u16* __restrict__ combh, u16* __restrict__ combl) {
  __shared__ u16 Ash[64][72], Asl[64][72], Vsh[64][72], Vsl[64][72];  // 36.9 KB
  __shared__ float scs_l[64][NC];                                     // 2 KB
  __shared__ float Of[64][66];                                        // 16.9 KB
  int i0 = blockIdx.x * 64;
  int h = blockIdx.y;
  int t = threadIdx.x, lane = t & 63, wave = t >> 6, wr = wave >> 1, wc = wave & 1;
  int lr = lane & 15, lk = (lane >> 4) << 3;

  // per-row softmax chunk scales
  if (t < 64) {
    int gi = i0 + t;
    float mc[NC], sc[NC], m = -3.0e38f;
    #pragma unroll
    for (int c = 0; c < NC; c++) {
      const float* p = msum + (((size_t)gi*NC + c)*NH + h)*2;
      mc[c] = p[0]; sc[c] = p[1];
      m = fmaxf(m, mc[c]);
    }
    float den = 0.f;
    #pragma unroll
    for (int c = 0; c < NC; c++) den += sc[c] * __expf(mc[c] - m);
    float inv = 1.f / den;
    #pragma unroll
    for (int c = 0; c < NC; c++) scs_l[t][c] = __expf(mc[c] - m) * inv;
  }
  __syncthreads();

  // pair_out combine -> comb cols 768..2304
  for (int e = t; e < 64*DPAIR; e += 256) {
    int m = e >> 7, d = e & 127;
    float s = 0.f;
    #pragma unroll
    for (int c = 0; c < NC; c++)
      s = fmaf(scs_l[m][c], pairpart[(((size_t)(i0+m)*NC + c)*NH + h)*DPAIR + d], s);
    u16 h_, l_; split_bf16(s, h_, l_);
    size_t dst = (size_t)(i0+m)*2304 + 768 + h*DPAIR + d;
    combh[dst] = h_; combl[dst] = l_;
  }

  f32x4 c00 = {0.f,0.f,0.f,0.f}, c01 = c00, c10 = c00, c11 = c00;
  for (int jc = 0; jc < 8; jc++) {
    int j0 = jc * 64;
    // stage normalized attention weights A[m][j]
    for (int e = t; e < 4096; e += 256) {
      int m = e >> 6, j = e & 63;
      float w = S[((size_t)h*LQ + i0 + m)*LQ + j0 + j] * scs_l[m][jc];
      u16 h_, l_; split_bf16(w, h_, l_);
      Ash[m][j] = h_; Asl[m][j] = l_;
    }
    // stage V^T[n][j]: n<32 = v, 32..55 = rotated vg, 56..63 = 0
    {
      int j = t & 63, ng = t >> 6;
      int gj = j0 + j;
      u16 h_, l_;
      if (ng < 2) {
        const float* vrow = C1 + (size_t)gj*NPP + 768 + h*32 + ng*16;
        #pragma unroll
        for (int q = 0; q < 16; q++) {
          split_bf16(vrow[q], h_, l_);
          Vsh[ng*16 + q][j] = h_; Vsl[ng*16 + q][j] = l_;
        }
      } else {
        const float* prow = C1 + (size_t)gj*NPP + 1440 + h*24;
        const float* R = rot + (size_t)gj*9;
        const float* tr = trans + (size_t)gj*3;
        int nbase = ng * 16;   // 32 or 48
        #pragma unroll
        for (int q = 0; q < 16; q++) {
          int n = nbase + q;
          float val = 0.f;
          if (n < 56) {
            int pp = (n - 32) / 3, rr = (n - 32) % 3;
            float x = prow[pp*3], y = prow[pp*3+1], z = prow[pp*3+2];
            val = fmaf(R[rr*3], x, fmaf(R[rr*3+1], y, fmaf(R[rr*3+2], z, tr[rr])));
          }
          split_bf16(val, h_, l_);
          Vsh[n][j] = h_; Vsl[n][j] = l_;
        }
      }
    }
    __syncthreads();
    #pragma unroll
    for (int ks = 0; ks < 64; ks += 32) {
      bf16x8 A0h = *(const bf16x8*)&Ash[wr*32 + lr][ks + lk];
      bf16x8 A1h = *(const bf16x8*)&Ash[wr*32 + 16 + lr][ks + lk];
      bf16x8 B0h = *(const bf16x8*)&Vsh[wc*32 + lr][ks + lk];
      bf16x8 B1h = *(const bf16x8*)&Vsh[wc*32 + 16 + lr][ks + lk];
      bf16x8 A0l = *(const bf16x8*)&Asl[wr*32 + lr][ks + lk];
      bf16x8 A1l = *(const bf16x8*)&Asl[wr*32 + 16 + lr][ks + lk];
      bf16x8 B0l = *(const bf16x8*)&Vsl[wc*32 + lr][ks + lk];
      bf16x8 B1l = *(const bf16x8*)&Vsl[wc*32 + 16 + lr][ks + lk];
      c00 = __builtin_amdgcn_mfma_f32_16x16x32_bf16(A0h, B0h, c00, 0, 0, 0);
      c01 = __builtin_amdgcn_mfma_f32_16x16x32_bf16(A0h, B1h, c01, 0, 0, 0);
      c10 = __builtin_amdgcn_mfma_f32_16x16x32_bf16(A1h, B0h, c10, 0, 0, 0);
      c11 = __builtin_amdgcn_mfma_f32_16x16x32_bf16(A1h, B1h, c11, 0, 0, 0);
      c00 = __builtin_amdgcn_mfma_f32_16x16x32_bf16(A0h, B0l, c00, 0, 0, 0);
      c01 = __builtin_amdgcn_mfma_f32_16x16x32_bf16(A0h, B1l, c01, 0, 0, 0);
      c10 = __builtin_amdgcn_mfma_f32_16x16x32_bf16(A1h, B0l, c10, 0, 0, 0);
      c11 = __builtin_amdgcn_mfma_f32_16x16x32_bf16(A1h, B1l, c11, 0, 0, 0);
      c00 = __builtin_amdgcn_mfma_f32_16x16x32_bf16(A0l, B0h, c00, 0, 0, 0);
      c01 = __builtin_amdgcn_mfma_f32_16x16x32_bf16(A0l, B1h, c01, 0, 0, 0);
      c10 = __builtin_amdgcn_mfma_f32_16x16x32_bf16(A1l, B0h, c10, 0, 0, 0);
      c11 = __builtin_amdgcn_mfma_f32_16x16x32_bf16(A1l, B1h, c11, 0, 0, 0);
    }
    __syncthreads();
  }

  // gather output tile in LDS
  int orow = (lane >> 4) << 2;
  #pragma unroll
  for (int r = 0; r < 4; r++) {
    Of[wr*32 + orow + r][wc*32 + lr]           = c00[r];
    Of[wr*32 + orow + r][wc*32 + 16 + lr]      = c01[r];
    Of[wr*32 + 16 + orow + r][wc*32 + lr]      = c10[r];
    Of[wr*32 + 16 + orow + r][wc*32 + 16 + lr] = c11[r];
  }
  __syncthreads();

  // avpts epilogue: seq part + point transform
  for (int e = t; e < 64*40; e += 256) {
    int w = e % 40, m = e / 40;
    int gi = i0 + m;
    u16 h_, l_;
    if (w < 32) {
      split_bf16(Of[m][w], h_, l_);
      combh[(size_t)gi*2304 + h*32 + w] = h_;
      combl[(size_t)gi*2304 + h*32 + w] = l_;
    } else {
      int pp = w - 32;
      float g0 = Of[m][32+pp*3], g1 = Of[m][32+pp*3+1], g2 = Of[m][32+pp*3+2];
      const float* R = rot + (size_t)gi*9;
      const float* tr = trans + (size_t)gi*3;
      float x = g0 - tr[0], y = g1 - tr[1], z = g2 - tr[2];
      float lx = fmaf(R[0],x, fmaf(R[3],y, R[6]*z));
      float ly = fmaf(R[1],x, fmaf(R[4],y, R[7]*z));
      float lz = fmaf(R[2],x, fmaf(R[5],y, R[8]*z));
      float nrm = sqrtf(fmaf(lx,lx, fmaf(ly,ly, lz*lz)));
      size_t dst = (size_t)gi*2304 + 384 + ((size_t)h*8 + pp)*4;
      split_bf16(nrm, h_, l_); combh[dst+0] = h_; combl[dst+0] = l_;
      split_bf16(lx,  h_, l_); combh[dst+1] = h_; combl[dst+1] = l_;
      split_bf16(ly,  h_, l_); combh[dst+2] = h_; combl[dst+2] = l_;
      split_bf16(lz,  h_, l_); combh[dst+3] = h_; combl[dst+3] = l_;
    }
  }
}

// ================================================================ launcher
extern "C" void kernel_launch(void* const* d_in, const int* in_sizes, int n_in,
                              void* d_out, int out_size, void* d_ws, size_t ws_size,
                              hipStream_t stream) {
  const float* single = (const float*)d_in[0];
  const float* pair   = (const float*)d_in[1];
  const float* rot    = (const float*)d_in[2];
  const float* trans  = (const float*)d_in[3];
  const float* mask   = (const float*)d_in[4];
  const float* ln_w   = (const float*)d_in[5];
  const float* ln_b   = (const float*)d_in[6];
  const float* Wq     = (const float*)d_in[7];
  const float* bq     = (const float*)d_in[8];
  const float* Wk     = (const float*)d_in[9];
  const float* bk     = (const float*)d_in[10];
  const float* Wv     = (const float*)d_in[11];
  const float* bv     = (const float*)d_in[12];
  const float* Wqp    = (const float*)d_in[13];
  const float* bqp    = (const float*)d_in[14];
  const float* Wkp    = (const float*)d_in[15];
  const float* bkp    = (const float*)d_in[16];
  const float* Wvp    = (const float*)d_in[17];
  const float* bvp    = (const float*)d_in[18];
  const float* Wpb    = (const float*)d_in[19];
  const float* bpb    = (const float*)d_in[20];
  const float* Wo     = (const float*)d_in[21];
  const float* bo     = (const float*)d_in[22];
  const float* w_c    = (const float*)d_in[23];
  const float* w_l    = (const float*)d_in[24];
  const float* gamma  = (const float*)d_in[25];
  float* out = (float*)d_out;

  float* p = (float*)d_ws;
  auto alloc = [&](size_t n) { float* r = p; p += n; return r; };
  u16* WcatTh = (u16*)alloc((size_t)NPP*DS/2);
  u16* WcatTl = (u16*)alloc((size_t)NPP*DS/2);
  u16* snh    = (u16*)alloc((size_t)LQ*DS/2);
  u16* snl    = (u16*)alloc((size_t)LQ*DS/2);
  u16* WoTh   = (u16*)alloc((size_t)DS*2304/2);
  u16* WoTl   = (u16*)alloc((size_t)DS*2304/2);
  u16* combh  = (u16*)alloc((size_t)LQ*2304/2);
  u16* combl  = (u16*)alloc((size_t)LQ*2304/2);
  float* bcat    = alloc(NPP);
  float* WpbT    = alloc((size_t)NH*DPAIR);
  float* C1      = alloc((size_t)LQ*NPP);
  float* S       = alloc((size_t)NH*LQ*LQ);
  float* pairpart= alloc((size_t)LQ*NC*NH*DPAIR);
  float* msum    = alloc((size_t)LQ*NC*NH*2);
  float* outpart = alloc((size_t)8*LQ*DS);

  k_prep<<<dim3(897), 256, 0, stream>>>(
      Wq, Wk, Wv, Wqp, Wkp, Wvp, bq, bk, bv, bqp, bkp, bvp, Wpb, Wo,
      single, ln_w, ln_b, WcatTh, WcatTl, bcat, WpbT, WoTh, WoTl, snh, snl);
  k_gemm_mfma<<<dim3(NPP/64, LQ/64, 1), 256, 0, stream>>>(
      snh, snl, WcatTh, WcatTl, bcat, C1, nullptr, LQ, NPP, DS);
  k_feat_logits<<<dim3(LQ/64, LQ/64, NH), 256, 0, stream>>>(
      C1, rot, trans, gamma, w_c, w_l, S);
  k_pair_chunk<<<dim3(LQ, NC), 256, 0, stream>>>(pair, WpbT, bpb, mask, S, pairpart, msum);
  k_attn_full<<<dim3(LQ/64, NH), 256, 0, stream>>>(
      S, msum, pairpart, C1, rot, trans, combh, combl);
  k_gemm_mfma<<<dim3(DS/64, LQ/64, 8), 256, 0, stream>>>(
      combh, combl, WoTh, WoTl, nullptr, nullptr, outpart, LQ, DS, 2304);
  k_reduce_bias<<<dim3((LQ*DS + 255)/256), 256, 0, stream>>>(outpart, bo, out, LQ*DS, DS, 8);
}